// Round 1
// baseline (2484.568 us; speedup 1.0000x reference)
//
#include <hip/hip_runtime.h>

#define N_ROWS 32768
#define DD 768
#define CC 1024

typedef unsigned short u16;
typedef __bf16 bf16x8 __attribute__((ext_vector_type(8)));
typedef float f32x4 __attribute__((ext_vector_type(4)));

__device__ inline unsigned f2bfu(float f){
  unsigned u = __float_as_uint(f);
  return (u + 0x7fffu + ((u >> 16) & 1u)) >> 16;   // RNE f32->bf16
}
__device__ inline float bf2f(u16 h){ return __uint_as_float(((unsigned)h) << 16); }

__device__ inline float wsum(float v){
  #pragma unroll
  for (int o = 32; o > 0; o >>= 1) v += __shfl_xor(v, o, 64);
  return v;
}
__device__ inline float wmaxr(float v){
  #pragma unroll
  for (int o = 32; o > 0; o >>= 1) v = fmaxf(v, __shfl_xor(v, o, 64));
  return v;
}

// ---------- f32 -> bf16 convert (element count divisible by 4) ----------
__global__ void k_conv(const float* __restrict__ in, u16* __restrict__ out, int n4){
  int i = blockIdx.x * 256 + threadIdx.x;
  if (i < n4){
    float4 f = ((const float4*)in)[i];
    unsigned lo = f2bfu(f.x) | (f2bfu(f.y) << 16);
    unsigned hi = f2bfu(f.z) | (f2bfu(f.w) << 16);
    ((uint2*)out)[i] = make_uint2(lo, hi);
  }
}

// ---------- history: counting sort over segments ----------
__global__ void k_count(const int* __restrict__ labels, int* __restrict__ cnt){
  int i = blockIdx.x * 256 + threadIdx.x;
  if (i < N_ROWS){
    int l = labels[i];
    int seg = (l >= 1) ? (l - 1) : (CC - 1);
    atomicAdd(&cnt[seg], 1);
  }
}

__global__ void k_scan(const int* __restrict__ cnt, int* __restrict__ offs){
  __shared__ int s[CC];
  int t = threadIdx.x;
  s[t] = cnt[t];
  __syncthreads();
  for (int d = 1; d < CC; d <<= 1){
    int v = (t >= d) ? s[t - d] : 0;
    __syncthreads();
    s[t] += v;
    __syncthreads();
  }
  offs[t] = s[t] - cnt[t];   // exclusive
}

__global__ void k_scatter(const int* __restrict__ labels, const int* __restrict__ offs,
                          int* __restrict__ cursor, int* __restrict__ rowlist){
  int i = blockIdx.x * 256 + threadIdx.x;
  if (i < N_ROWS){
    int l = labels[i];
    int seg = (l >= 1) ? (l - 1) : (CC - 1);
    int p = atomicAdd(&cursor[seg], 1);
    rowlist[offs[seg] + p] = i;
  }
}

// block b==0: zero column 0 of vT (v_pad row for class 0)
// block b>=1: segment seg=b-1 -> v_pad row b -> vT[:, b]
__global__ void k_v(const float* __restrict__ x, const float* __restrict__ hist,
                    const int* __restrict__ hcnt, const int* __restrict__ cnt,
                    const int* __restrict__ offs, const int* __restrict__ rowlist,
                    u16* __restrict__ vT)
{
  int b = blockIdx.x, t = threadIdx.x;
  if (b == 0){
    for (int d = t; d < DD; d += 256) vT[(size_t)d * CC] = 0;
    return;
  }
  int seg = b - 1;
  int n = cnt[seg], base = offs[seg];
  float a0 = 0.f, a1 = 0.f, a2 = 0.f;
  for (int r = 0; r < n; ++r){
    const float* xr = x + (size_t)rowlist[base + r] * DD;
    a0 += xr[t]; a1 += xr[t + 256]; a2 += xr[t + 512];
  }
  int nc = hcnt[seg] + (n > 0 ? 1 : 0);
  int e = nc < 1 ? 1 : nc;
  float denom = 1.0f - powf(0.9f, (float)e);
  float sc = 0.1f / denom;                 // (1-MU)/denom
  float inv_n = (n > 0) ? 1.0f / (float)n : 0.f;
  {
    float h = hist[(size_t)seg * DD + t];
    float nh = (n > 0) ? 0.9f * h + a0 * inv_n : h;
    vT[(size_t)t * CC + b] = (u16)f2bfu(nh * sc);
  }
  {
    float h = hist[(size_t)seg * DD + t + 256];
    float nh = (n > 0) ? 0.9f * h + a1 * inv_n : h;
    vT[(size_t)(t + 256) * CC + b] = (u16)f2bfu(nh * sc);
  }
  {
    float h = hist[(size_t)seg * DD + t + 512];
    float nh = (n > 0) ? 0.9f * h + a2 * inv_n : h;
    vT[(size_t)(t + 512) * CC + b] = (u16)f2bfu(nh * sc);
  }
}

// ---------- gate g = 0.5*sigmoid(x . Wg + bg), one wave per row ----------
__global__ void k_g(const float* __restrict__ x, const float* __restrict__ Wg,
                    const float* __restrict__ bg, float* __restrict__ g){
  int row = (blockIdx.x * 256 + threadIdx.x) >> 6;
  int lane = threadIdx.x & 63;
  if (row >= N_ROWS) return;
  const float* xr = x + (size_t)row * DD;
  float s = 0.f;
  #pragma unroll
  for (int j = 0; j < 12; j++) s += xr[lane + 64 * j] * Wg[lane + 64 * j];
  s = wsum(s);
  if (lane == 0) g[row] = 0.5f / (1.0f + expf(-(s + bg[0])));
}

// ---------- bf16 NT MFMA GEMM: C[i][j] = sum_k A[i][k]*B[j][k] ----------
// 128x128 tile, BK=32, 256 threads = 4 waves (2x2), reg-staged LDS.
// EPI: 0 = +bias -> bf16 ; 1 = gelu(.+bias) -> bf16 ;
//      2 = mixed = g*x + (1-g)*acc -> bf16 ; 3 = raw f32 out
template<int EPI>
__global__ __launch_bounds__(256) void gemm_nt(
    const u16* __restrict__ A, const u16* __restrict__ B,
    int K, int NC,
    const float* __restrict__ bias, const float* __restrict__ gvec,
    const float* __restrict__ xf32, u16* __restrict__ outb, float* __restrict__ outf)
{
  __shared__ u16 lA[128 * 32];
  __shared__ u16 lB[128 * 32];
  const int t = threadIdx.x;
  const int lane = t & 63;
  const int w = t >> 6;
  const int wr = w >> 1, wc = w & 1;
  const size_t row0 = (size_t)blockIdx.y * 128;
  const size_t col0 = (size_t)blockIdx.x * 128;

  const int sr = t >> 2;            // staging row within half-tile
  const int sc = (t & 3) * 8;       // staging k-offset (8 bf16 = 16B)
  const u16* Ag0 = A + (row0 + sr) * K + sc;
  const u16* Ag1 = A + (row0 + sr + 64) * K + sc;
  const u16* Bg0 = B + (col0 + sr) * K + sc;
  const u16* Bg1 = B + (col0 + sr + 64) * K + sc;

  f32x4 acc[4][4] = {};

  int4 va0 = *(const int4*)Ag0;
  int4 va1 = *(const int4*)Ag1;
  int4 vb0 = *(const int4*)Bg0;
  int4 vb1 = *(const int4*)Bg1;

  const int nkt = K >> 5;
  for (int kt = 0; kt < nkt; ++kt){
    __syncthreads();
    *(int4*)&lA[t * 8]         = va0;
    *(int4*)&lA[(t + 256) * 8] = va1;
    *(int4*)&lB[t * 8]         = vb0;
    *(int4*)&lB[(t + 256) * 8] = vb1;
    __syncthreads();
    if (kt + 1 < nkt){
      int ko = (kt + 1) << 5;
      va0 = *(const int4*)(Ag0 + ko);
      va1 = *(const int4*)(Ag1 + ko);
      vb0 = *(const int4*)(Bg0 + ko);
      vb1 = *(const int4*)(Bg1 + ko);
    }
    const int kel = (lane >> 4) * 8;   // element offset within row (k)
    bf16x8 fa[4], fb[4];
    #pragma unroll
    for (int m = 0; m < 4; m++){
      int r = wr * 64 + m * 16 + (lane & 15);
      fa[m] = *(const bf16x8*)((const void*)&lA[r * 32 + kel]);
    }
    #pragma unroll
    for (int n = 0; n < 4; n++){
      int r = wc * 64 + n * 16 + (lane & 15);
      fb[n] = *(const bf16x8*)((const void*)&lB[r * 32 + kel]);
    }
    #pragma unroll
    for (int m = 0; m < 4; m++)
      #pragma unroll
      for (int n = 0; n < 4; n++)
        acc[m][n] = __builtin_amdgcn_mfma_f32_16x16x32_bf16(fa[m], fb[n], acc[m][n], 0, 0, 0);
  }

  // epilogue: C/D layout col=lane&15, row=(lane>>4)*4+q  [m89/m91 verified]
  #pragma unroll
  for (int m = 0; m < 4; m++){
    size_t gr0 = row0 + (size_t)(wr * 64 + m * 16 + (lane >> 4) * 4);
    #pragma unroll
    for (int n = 0; n < 4; n++){
      size_t gc = col0 + (size_t)(wc * 64 + n * 16 + (lane & 15));
      #pragma unroll
      for (int q = 0; q < 4; q++){
        size_t gr = gr0 + q;
        float v = acc[m][n][q];
        if constexpr (EPI == 0){
          outb[gr * NC + gc] = (u16)f2bfu(v + bias[gc]);
        } else if constexpr (EPI == 1){
          float z = v + bias[gc];
          float ge = 0.5f * z * (1.0f + erff(z * 0.70710678118654752f));
          outb[gr * NC + gc] = (u16)f2bfu(ge);
        } else if constexpr (EPI == 2){
          float gg = gvec[gr];
          float xv = xf32[gr * DD + gc];
          outb[gr * NC + gc] = (u16)f2bfu(gg * xv + (1.0f - gg) * v);
        } else {
          outf[gr * NC + gc] = v;
        }
      }
    }
  }
}

// ---------- row stats: CE(ctx), MSE partial, softmax(wlog)->w (bf16) ----------
// NOTE: wout may alias ctxb (read-to-regs happens before stores; no restrict on
// ctxb/wlogb/wout so the compiler must preserve load-before-store order).
__global__ void k_stats(const u16* ctxb, const u16* wlogb, const int* __restrict__ labels,
                        u16* wout, float* __restrict__ accv)
{
  int row = (blockIdx.x * 256 + threadIdx.x) >> 6;
  int lane = threadIdx.x & 63;
  if (row >= N_ROWS) return;
  const u16* cr = ctxb + (size_t)row * CC;
  const u16* wr = wlogb + (size_t)row * CC;
  float c[16], wl[16];
  #pragma unroll
  for (int j = 0; j < 16; j++){
    c[j]  = bf2f(cr[lane + 64 * j]);
    wl[j] = bf2f(wr[lane + 64 * j]);
  }
  int lbl = labels[row];
  int valid = (lbl >= 0);

  float ms = 0.f;
  #pragma unroll
  for (int j = 0; j < 16; j++){ float d = c[j] - wl[j]; ms += d * d; }
  ms = wsum(ms);

  float m1 = c[0];
  #pragma unroll
  for (int j = 1; j < 16; j++) m1 = fmaxf(m1, c[j]);
  m1 = wmaxr(m1);
  float s1 = 0.f;
  #pragma unroll
  for (int j = 0; j < 16; j++) s1 += expf(c[j] - m1);
  s1 = wsum(s1);

  float m2 = wl[0];
  #pragma unroll
  for (int j = 1; j < 16; j++) m2 = fmaxf(m2, wl[j]);
  m2 = wmaxr(m2);
  float s2 = 0.f;
  #pragma unroll
  for (int j = 0; j < 16; j++) s2 += expf(wl[j] - m2);
  s2 = wsum(s2);
  float inv = 1.0f / s2;

  u16* wo = wout + (size_t)row * CC;
  #pragma unroll
  for (int j = 0; j < 16; j++) wo[lane + 64 * j] = (u16)f2bfu(expf(wl[j] - m2) * inv);

  if (valid){
    float cl = 0.f; int hit = 0;
    #pragma unroll
    for (int j = 0; j < 16; j++){ if (lbl == lane + 64 * j){ cl = c[j]; hit = 1; } }
    if (hit) atomicAdd(&accv[0], m1 + logf(s1) - cl);   // ce_ctx partial
  }
  if (lane == 0){
    if (valid) atomicAdd(&accv[1], ms);                 // mse partial (masked)
    atomicAdd(&accv[3], valid ? 1.0f : 0.0f);           // nvalid
  }
}

// ---------- CE over final logits (f32, in d_out+1) ----------
__global__ void k_celog(const float* __restrict__ logits, const int* __restrict__ labels,
                        float* __restrict__ accv)
{
  int row = (blockIdx.x * 256 + threadIdx.x) >> 6;
  int lane = threadIdx.x & 63;
  if (row >= N_ROWS) return;
  const float* lr = logits + (size_t)row * CC;
  float v[16];
  #pragma unroll
  for (int j = 0; j < 16; j++) v[j] = lr[lane + 64 * j];
  int lbl = labels[row];
  if (lbl < 0) return;   // wave-uniform
  float m = v[0];
  #pragma unroll
  for (int j = 1; j < 16; j++) m = fmaxf(m, v[j]);
  m = wmaxr(m);
  float s = 0.f;
  #pragma unroll
  for (int j = 0; j < 16; j++) s += expf(v[j] - m);
  s = wsum(s);
  float cl = 0.f; int hit = 0;
  #pragma unroll
  for (int j = 0; j < 16; j++){ if (lbl == lane + 64 * j){ cl = v[j]; hit = 1; } }
  if (hit) atomicAdd(&accv[2], m + logf(s) - cl);
}

__global__ void k_final(const float* __restrict__ accv, float* __restrict__ out){
  float nv = fmaxf(accv[3], 1.0f);
  out[0] = accv[2] / nv + accv[0] / nv + 0.5f * (accv[1] / (nv * (float)CC));
}

extern "C" void kernel_launch(void* const* d_in, const int* in_sizes, int n_in,
                              void* d_out, int out_size, void* d_ws, size_t ws_size,
                              hipStream_t stream)
{
  (void)in_sizes; (void)n_in; (void)out_size; (void)ws_size;
  const float* x     = (const float*)d_in[0];
  const float* xctx  = (const float*)d_in[1];
  const int*   labels= (const int*)d_in[2];
  const float* cls   = (const float*)d_in[3];
  const float* W_ctx = (const float*)d_in[4];
  const float* b_ctx = (const float*)d_in[5];
  const float* W_g   = (const float*)d_in[6];
  const float* b_g   = (const float*)d_in[7];
  const float* W1    = (const float*)d_in[8];
  const float* b1    = (const float*)d_in[9];
  const float* W2    = (const float*)d_in[10];
  const float* b2    = (const float*)d_in[11];
  const float* hist  = (const float*)d_in[12];
  const int*   hcnt  = (const int*)d_in[13];
  float* out = (float*)d_out;

  char* p = (char*)d_ws;
  auto alloc = [&](size_t b)->char*{ char* r = p; p += (b + 255) & ~(size_t)255; return r; };
  u16* R1     = (u16*)alloc((size_t)N_ROWS * DD * 2);   // xctx_bf -> h_bf
  u16* R2     = (u16*)alloc((size_t)N_ROWS * DD * 2);   // x_bf -> mixed_bf
  u16* R3     = (u16*)alloc((size_t)N_ROWS * CC * 2);   // ctx_bf -> w_bf (aliased)
  u16* R4     = (u16*)alloc((size_t)N_ROWS * CC * 2);   // wlog_bf
  u16* Wctx_b = (u16*)alloc((size_t)CC * DD * 2);
  u16* W1_b   = (u16*)alloc((size_t)DD * DD * 2);
  u16* W2_b   = (u16*)alloc((size_t)CC * DD * 2);
  u16* cls_b  = (u16*)alloc((size_t)CC * DD * 2);
  u16* vT     = (u16*)alloc((size_t)DD * CC * 2);       // [D][C] bf16, col0 = 0
  float* g    = (float*)alloc((size_t)N_ROWS * 4);
  char* zbase = p;
  int* cnt     = (int*)alloc(CC * 4);
  int* offs    = (int*)alloc(CC * 4);
  int* cursor  = (int*)alloc(CC * 4);
  int* rowlist = (int*)alloc(N_ROWS * 4);
  float* accv  = (float*)alloc(64);
  size_t zbytes = (size_t)(p - zbase);
  hipMemsetAsync(zbase, 0, zbytes, stream);

  // bf16 conversions
  k_conv<<<(N_ROWS * DD / 4 + 255) / 256, 256, 0, stream>>>(x, R2, N_ROWS * DD / 4);
  k_conv<<<(N_ROWS * DD / 4 + 255) / 256, 256, 0, stream>>>(xctx, R1, N_ROWS * DD / 4);
  k_conv<<<(CC * DD / 4 + 255) / 256, 256, 0, stream>>>(W_ctx, Wctx_b, CC * DD / 4);
  k_conv<<<(DD * DD / 4 + 255) / 256, 256, 0, stream>>>(W1, W1_b, DD * DD / 4);
  k_conv<<<(CC * DD / 4 + 255) / 256, 256, 0, stream>>>(W2, W2_b, CC * DD / 4);
  k_conv<<<(CC * DD / 4 + 255) / 256, 256, 0, stream>>>(cls, cls_b, CC * DD / 4);

  // history EMA -> vT
  k_count  <<<N_ROWS / 256, 256, 0, stream>>>(labels, cnt);
  k_scan   <<<1, CC, 0, stream>>>(cnt, offs);
  k_scatter<<<N_ROWS / 256, 256, 0, stream>>>(labels, offs, cursor, rowlist);
  k_v      <<<CC, 256, 0, stream>>>(x, hist, hcnt, cnt, offs, rowlist, vT);

  // gate
  k_g<<<N_ROWS / 4, 256, 0, stream>>>(x, W_g, b_g, g);

  // GEMM chain
  gemm_nt<0><<<dim3(CC / 128, N_ROWS / 128), 256, 0, stream>>>(R1, Wctx_b, DD, CC, b_ctx, nullptr, nullptr, R3, nullptr);
  gemm_nt<1><<<dim3(DD / 128, N_ROWS / 128), 256, 0, stream>>>(R2, W1_b,   DD, DD, b1,    nullptr, nullptr, R1, nullptr);
  gemm_nt<0><<<dim3(CC / 128, N_ROWS / 128), 256, 0, stream>>>(R1, W2_b,   DD, CC, b2,    nullptr, nullptr, R4, nullptr);

  k_stats<<<N_ROWS / 4, 256, 0, stream>>>(R3, R4, labels, R3, accv);

  gemm_nt<2><<<dim3(DD / 128, N_ROWS / 128), 256, 0, stream>>>(R3, vT,    CC, DD, nullptr, g, x, R2, nullptr);
  gemm_nt<3><<<dim3(CC / 128, N_ROWS / 128), 256, 0, stream>>>(R2, cls_b, DD, CC, nullptr, nullptr, nullptr, nullptr, out + 1);

  // losses
  k_celog<<<N_ROWS / 4, 256, 0, stream>>>(out + 1, labels, accv);
  k_final<<<1, 1, 0, stream>>>(accv, out);
}

// Round 2
// 924.782 us; speedup vs baseline: 2.6867x; 2.6867x over previous
//
#include <hip/hip_runtime.h>

#define N_ROWS 32768
#define DD 768
#define CC 1024

typedef unsigned short u16;
typedef __bf16 bf16x8 __attribute__((ext_vector_type(8)));
typedef float f32x4 __attribute__((ext_vector_type(4)));

__device__ inline unsigned f2bfu(float f){
  unsigned u = __float_as_uint(f);
  return (u + 0x7fffu + ((u >> 16) & 1u)) >> 16;   // RNE f32->bf16
}
__device__ inline float bf2f(u16 h){ return __uint_as_float(((unsigned)h) << 16); }

__device__ inline float wsum(float v){
  #pragma unroll
  for (int o = 32; o > 0; o >>= 1) v += __shfl_xor(v, o, 64);
  return v;
}
__device__ inline float wmaxr(float v){
  #pragma unroll
  for (int o = 32; o > 0; o >>= 1) v = fmaxf(v, __shfl_xor(v, o, 64));
  return v;
}

// async global(16B per lane) -> LDS; dest must be wave-uniform base + lane*16
__device__ __forceinline__ void gl2lds16(const u16* g, u16* l){
  __builtin_amdgcn_global_load_lds(
      (const __attribute__((address_space(1))) void*)g,
      (__attribute__((address_space(3))) void*)l, 16, 0, 0);
}

__device__ inline void unpack8(uint4 v, float* f){
  unsigned a0 = v.x, a1 = v.y, a2 = v.z, a3 = v.w;
  f[0] = __uint_as_float(a0 << 16); f[1] = __uint_as_float(a0 & 0xffff0000u);
  f[2] = __uint_as_float(a1 << 16); f[3] = __uint_as_float(a1 & 0xffff0000u);
  f[4] = __uint_as_float(a2 << 16); f[5] = __uint_as_float(a2 & 0xffff0000u);
  f[6] = __uint_as_float(a3 << 16); f[7] = __uint_as_float(a3 & 0xffff0000u);
}

// ---------- f32 -> bf16 convert (element count divisible by 4) ----------
__global__ void k_conv(const float* __restrict__ in, u16* __restrict__ out, int n4){
  int i = blockIdx.x * 256 + threadIdx.x;
  if (i < n4){
    float4 f = ((const float4*)in)[i];
    unsigned lo = f2bfu(f.x) | (f2bfu(f.y) << 16);
    unsigned hi = f2bfu(f.z) | (f2bfu(f.w) << 16);
    ((uint2*)out)[i] = make_uint2(lo, hi);
  }
}

// ---------- history: counting sort over segments ----------
__global__ void k_count(const int* __restrict__ labels, int* __restrict__ cnt){
  int i = blockIdx.x * 256 + threadIdx.x;
  if (i < N_ROWS){
    int l = labels[i];
    int seg = (l >= 1) ? (l - 1) : (CC - 1);
    atomicAdd(&cnt[seg], 1);
  }
}

__global__ void k_scan(const int* __restrict__ cnt, int* __restrict__ offs){
  __shared__ int s[CC];
  int t = threadIdx.x;
  s[t] = cnt[t];
  __syncthreads();
  for (int d = 1; d < CC; d <<= 1){
    int v = (t >= d) ? s[t - d] : 0;
    __syncthreads();
    s[t] += v;
    __syncthreads();
  }
  offs[t] = s[t] - cnt[t];   // exclusive
}

__global__ void k_scatter(const int* __restrict__ labels, const int* __restrict__ offs,
                          int* __restrict__ cursor, int* __restrict__ rowlist){
  int i = blockIdx.x * 256 + threadIdx.x;
  if (i < N_ROWS){
    int l = labels[i];
    int seg = (l >= 1) ? (l - 1) : (CC - 1);
    int p = atomicAdd(&cursor[seg], 1);
    rowlist[offs[seg] + p] = i;
  }
}

// block b==0: zero column 0 of vT; block b>=1: segment seg=b-1 -> vT[:, b]
__global__ void k_v(const float* __restrict__ x, const float* __restrict__ hist,
                    const int* __restrict__ hcnt, const int* __restrict__ cnt,
                    const int* __restrict__ offs, const int* __restrict__ rowlist,
                    u16* __restrict__ vT)
{
  int b = blockIdx.x, t = threadIdx.x;
  if (b == 0){
    for (int d = t; d < DD; d += 256) vT[(size_t)d * CC] = 0;
    return;
  }
  int seg = b - 1;
  int n = cnt[seg], base = offs[seg];
  float a0 = 0.f, a1 = 0.f, a2 = 0.f;
  for (int r = 0; r < n; ++r){
    const float* xr = x + (size_t)rowlist[base + r] * DD;
    a0 += xr[t]; a1 += xr[t + 256]; a2 += xr[t + 512];
  }
  int nc = hcnt[seg] + (n > 0 ? 1 : 0);
  int e = nc < 1 ? 1 : nc;
  float denom = 1.0f - powf(0.9f, (float)e);
  float sc = 0.1f / denom;                 // (1-MU)/denom
  float inv_n = (n > 0) ? 1.0f / (float)n : 0.f;
  {
    float h = hist[(size_t)seg * DD + t];
    float nh = (n > 0) ? 0.9f * h + a0 * inv_n : h;
    vT[(size_t)t * CC + b] = (u16)f2bfu(nh * sc);
  }
  {
    float h = hist[(size_t)seg * DD + t + 256];
    float nh = (n > 0) ? 0.9f * h + a1 * inv_n : h;
    vT[(size_t)(t + 256) * CC + b] = (u16)f2bfu(nh * sc);
  }
  {
    float h = hist[(size_t)seg * DD + t + 512];
    float nh = (n > 0) ? 0.9f * h + a2 * inv_n : h;
    vT[(size_t)(t + 512) * CC + b] = (u16)f2bfu(nh * sc);
  }
}

// ---------- gate g = 0.5*sigmoid(x . Wg + bg), one wave per row ----------
__global__ void k_g(const float* __restrict__ x, const float* __restrict__ Wg,
                    const float* __restrict__ bg, float* __restrict__ g){
  int row = (blockIdx.x * 256 + threadIdx.x) >> 6;
  int lane = threadIdx.x & 63;
  if (row >= N_ROWS) return;
  const float* xr = x + (size_t)row * DD;
  float s = 0.f;
  #pragma unroll
  for (int j = 0; j < 12; j++) s += xr[lane + 64 * j] * Wg[lane + 64 * j];
  s = wsum(s);
  if (lane == 0) g[row] = 0.5f / (1.0f + expf(-(s + bg[0])));
}

// ---------- bf16 NT MFMA GEMM: C[i][j] = sum_k A[i][k]*B[j][k] ----------
// 128x128 tile, BK=32, 4 waves (2x2), global_load_lds width-16 staging (m97).
template<int EPI>
__global__ __launch_bounds__(256) void gemm_nt(
    const u16* __restrict__ A, const u16* __restrict__ B,
    int K, int NC,
    const float* __restrict__ bias, const float* __restrict__ gvec,
    const float* __restrict__ xf32, u16* __restrict__ outb, float* __restrict__ outf)
{
  __shared__ u16 lA[128 * 32];
  __shared__ u16 lB[128 * 32];
  const int t = threadIdx.x;
  const int lane = t & 63;
  const int w = t >> 6;
  const int wr = w >> 1, wc = w & 1;
  const size_t row0 = (size_t)blockIdx.y * 128;
  const size_t col0 = (size_t)blockIdx.x * 128;

  const int sr = t >> 2;            // staging row within half-tile
  const int sc = (t & 3) * 8;       // staging k-offset (8 bf16 = 16B)
  const u16* Ag0 = A + (row0 + sr) * K + sc;
  const u16* Ag1 = A + (row0 + sr + 64) * K + sc;
  const u16* Bg0 = B + (col0 + sr) * K + sc;
  const u16* Bg1 = B + (col0 + sr + 64) * K + sc;
  u16* dA0 = &lA[t * 8];
  u16* dA1 = &lA[(t + 256) * 8];
  u16* dB0 = &lB[t * 8];
  u16* dB1 = &lB[(t + 256) * 8];

  f32x4 acc[4][4] = {};

  const int nkt = K >> 5;
  for (int kt = 0; kt < nkt; ++kt){
    __syncthreads();                 // prev compute done before LDS overwrite
    const int ko = kt << 5;
    gl2lds16(Ag0 + ko, dA0);
    gl2lds16(Ag1 + ko, dA1);
    gl2lds16(Bg0 + ko, dB0);
    gl2lds16(Bg1 + ko, dB1);
    __syncthreads();                 // compiler drains vmcnt(0) before barrier

    const int kel = (lane >> 4) * 8;
    bf16x8 fa[4], fb[4];
    #pragma unroll
    for (int m = 0; m < 4; m++){
      int r = wr * 64 + m * 16 + (lane & 15);
      fa[m] = *(const bf16x8*)((const void*)&lA[r * 32 + kel]);
    }
    #pragma unroll
    for (int n = 0; n < 4; n++){
      int r = wc * 64 + n * 16 + (lane & 15);
      fb[n] = *(const bf16x8*)((const void*)&lB[r * 32 + kel]);
    }
    #pragma unroll
    for (int m = 0; m < 4; m++)
      #pragma unroll
      for (int n = 0; n < 4; n++)
        acc[m][n] = __builtin_amdgcn_mfma_f32_16x16x32_bf16(fa[m], fb[n], acc[m][n], 0, 0, 0);
  }

  // epilogue: C/D layout col=lane&15, row=(lane>>4)*4+q  [m89/m91 verified]
  #pragma unroll
  for (int m = 0; m < 4; m++){
    size_t gr0 = row0 + (size_t)(wr * 64 + m * 16 + (lane >> 4) * 4);
    #pragma unroll
    for (int n = 0; n < 4; n++){
      size_t gc = col0 + (size_t)(wc * 64 + n * 16 + (lane & 15));
      #pragma unroll
      for (int q = 0; q < 4; q++){
        size_t gr = gr0 + q;
        float v = acc[m][n][q];
        if constexpr (EPI == 0){
          outb[gr * NC + gc] = (u16)f2bfu(v + bias[gc]);
        } else if constexpr (EPI == 1){
          float z = v + bias[gc];
          float ge = 0.5f * z * (1.0f + erff(z * 0.70710678118654752f));
          outb[gr * NC + gc] = (u16)f2bfu(ge);
        } else if constexpr (EPI == 2){
          float gg = gvec[gr];
          float xv = xf32[gr * DD + gc];
          outb[gr * NC + gc] = (u16)f2bfu(gg * xv + (1.0f - gg) * v);
        } else {
          outf[gr * NC + gc] = v;
        }
      }
    }
  }
}

// ---------- row stats: CE(ctx), MSE partial, softmax(wlog)->w (bf16) ----------
// Grid-stride: 1024 blocks x 4 waves, 8 rows/wave; ONE atomic per block.
// wout aliases ctxb (loads precede stores; pointers non-restrict).
__global__ __launch_bounds__(256) void k_stats(const u16* ctxb, const u16* wlogb,
                        const int* __restrict__ labels, u16* wout,
                        float* __restrict__ accv)
{
  const int lane = threadIdx.x & 63;
  const int wid = threadIdx.x >> 6;
  float ce = 0.f, msacc = 0.f, nv = 0.f;

  for (int row = blockIdx.x * 4 + wid; row < N_ROWS; row += 1024 * 4){
    const u16* cr = ctxb + (size_t)row * CC;
    const u16* wrp = wlogb + (size_t)row * CC;
    uint4 cv0 = *(const uint4*)(cr + lane * 8);
    uint4 cv1 = *(const uint4*)(cr + 512 + lane * 8);
    uint4 wv0 = *(const uint4*)(wrp + lane * 8);
    uint4 wv1 = *(const uint4*)(wrp + 512 + lane * 8);
    float c[16], wl[16];
    unpack8(cv0, c); unpack8(cv1, c + 8);
    unpack8(wv0, wl); unpack8(wv1, wl + 8);
    int lbl = labels[row];
    int valid = (lbl >= 0);

    float ms = 0.f;
    #pragma unroll
    for (int j = 0; j < 16; j++){ float d = c[j] - wl[j]; ms += d * d; }
    ms = wsum(ms);

    float m1 = c[0], m2 = wl[0];
    #pragma unroll
    for (int j = 1; j < 16; j++){ m1 = fmaxf(m1, c[j]); m2 = fmaxf(m2, wl[j]); }
    m1 = wmaxr(m1); m2 = wmaxr(m2);
    float s1 = 0.f, s2 = 0.f;
    float p[16];
    #pragma unroll
    for (int j = 0; j < 16; j++){
      s1 += expf(c[j] - m1);
      p[j] = expf(wl[j] - m2);
      s2 += p[j];
    }
    s1 = wsum(s1); s2 = wsum(s2);
    float inv = 1.0f / s2;

    // softmax(wlog) -> bf16 store (contiguous 16B per lane)
    unsigned pk[8];
    #pragma unroll
    for (int i = 0; i < 8; i++)
      pk[i] = f2bfu(p[2 * i] * inv) | (f2bfu(p[2 * i + 1] * inv) << 16);
    u16* wo = wout + (size_t)row * CC;
    *(uint4*)(wo + lane * 8) = make_uint4(pk[0], pk[1], pk[2], pk[3]);
    *(uint4*)(wo + 512 + lane * 8) = make_uint4(pk[4], pk[5], pk[6], pk[7]);

    // label logit (one lane hits; broadcast via wsum)
    float clp = 0.f;
    #pragma unroll
    for (int j = 0; j < 8; j++){
      if (lbl == lane * 8 + j) clp = c[j];
      if (lbl == 512 + lane * 8 + j) clp = c[8 + j];
    }
    float cls = wsum(clp);

    if (valid){
      ce += m1 + logf(s1) - cls;
      msacc += ms;
      nv += 1.0f;
    }
  }

  __shared__ float red[3][4];
  if (lane == 0){ red[0][wid] = ce; red[1][wid] = msacc; red[2][wid] = nv; }
  __syncthreads();
  if (threadIdx.x == 0){
    atomicAdd(&accv[0], red[0][0] + red[0][1] + red[0][2] + red[0][3]);
    atomicAdd(&accv[1], red[1][0] + red[1][1] + red[1][2] + red[1][3]);
    atomicAdd(&accv[3], red[2][0] + red[2][1] + red[2][2] + red[2][3]);
  }
}

// ---------- CE over final logits (f32, unaligned base => scalar loads) ----------
__global__ __launch_bounds__(256) void k_celog(const float* __restrict__ logits,
                        const int* __restrict__ labels, float* __restrict__ accv)
{
  const int lane = threadIdx.x & 63;
  const int wid = threadIdx.x >> 6;
  float ce = 0.f;
  for (int row = blockIdx.x * 4 + wid; row < N_ROWS; row += 1024 * 4){
    const float* lr = logits + (size_t)row * CC;
    float v[16];
    #pragma unroll
    for (int j = 0; j < 16; j++) v[j] = lr[lane + 64 * j];
    int lbl = labels[row];
    if (lbl < 0) continue;   // wave-uniform
    float m = v[0];
    #pragma unroll
    for (int j = 1; j < 16; j++) m = fmaxf(m, v[j]);
    m = wmaxr(m);
    float s = 0.f;
    #pragma unroll
    for (int j = 0; j < 16; j++) s += expf(v[j] - m);
    s = wsum(s);
    float clp = 0.f;
    #pragma unroll
    for (int j = 0; j < 16; j++){ if (lbl == lane + 64 * j) clp = v[j]; }
    float cls = wsum(clp);
    ce += m + logf(s) - cls;
  }
  __shared__ float red[4];
  if (lane == 0) red[wid] = ce;
  __syncthreads();
  if (threadIdx.x == 0)
    atomicAdd(&accv[2], red[0] + red[1] + red[2] + red[3]);
}

__global__ void k_final(const float* __restrict__ accv, float* __restrict__ out){
  float nv = fmaxf(accv[3], 1.0f);
  out[0] = accv[2] / nv + accv[0] / nv + 0.5f * (accv[1] / (nv * (float)CC));
}

extern "C" void kernel_launch(void* const* d_in, const int* in_sizes, int n_in,
                              void* d_out, int out_size, void* d_ws, size_t ws_size,
                              hipStream_t stream)
{
  (void)in_sizes; (void)n_in; (void)out_size; (void)ws_size;
  const float* x     = (const float*)d_in[0];
  const float* xctx  = (const float*)d_in[1];
  const int*   labels= (const int*)d_in[2];
  const float* cls   = (const float*)d_in[3];
  const float* W_ctx = (const float*)d_in[4];
  const float* b_ctx = (const float*)d_in[5];
  const float* W_g   = (const float*)d_in[6];
  const float* b_g   = (const float*)d_in[7];
  const float* W1    = (const float*)d_in[8];
  const float* b1    = (const float*)d_in[9];
  const float* W2    = (const float*)d_in[10];
  const float* b2    = (const float*)d_in[11];
  const float* hist  = (const float*)d_in[12];
  const int*   hcnt  = (const int*)d_in[13];
  float* out = (float*)d_out;

  char* p = (char*)d_ws;
  auto alloc = [&](size_t b)->char*{ char* r = p; p += (b + 255) & ~(size_t)255; return r; };
  u16* R1     = (u16*)alloc((size_t)N_ROWS * DD * 2);   // xctx_bf -> h_bf
  u16* R2     = (u16*)alloc((size_t)N_ROWS * DD * 2);   // x_bf -> mixed_bf
  u16* R3     = (u16*)alloc((size_t)N_ROWS * CC * 2);   // ctx_bf -> w_bf (aliased)
  u16* R4     = (u16*)alloc((size_t)N_ROWS * CC * 2);   // wlog_bf
  u16* Wctx_b = (u16*)alloc((size_t)CC * DD * 2);
  u16* W1_b   = (u16*)alloc((size_t)DD * DD * 2);
  u16* W2_b   = (u16*)alloc((size_t)CC * DD * 2);
  u16* cls_b  = (u16*)alloc((size_t)CC * DD * 2);
  u16* vT     = (u16*)alloc((size_t)DD * CC * 2);       // [D][C] bf16, col0 = 0
  float* g    = (float*)alloc((size_t)N_ROWS * 4);
  char* zbase = p;
  int* cnt     = (int*)alloc(CC * 4);
  int* offs    = (int*)alloc(CC * 4);
  int* cursor  = (int*)alloc(CC * 4);
  int* rowlist = (int*)alloc(N_ROWS * 4);
  float* accv  = (float*)alloc(64);
  size_t zbytes = (size_t)(p - zbase);
  hipMemsetAsync(zbase, 0, zbytes, stream);

  // bf16 conversions
  k_conv<<<(N_ROWS * DD / 4 + 255) / 256, 256, 0, stream>>>(x, R2, N_ROWS * DD / 4);
  k_conv<<<(N_ROWS * DD / 4 + 255) / 256, 256, 0, stream>>>(xctx, R1, N_ROWS * DD / 4);
  k_conv<<<(CC * DD / 4 + 255) / 256, 256, 0, stream>>>(W_ctx, Wctx_b, CC * DD / 4);
  k_conv<<<(DD * DD / 4 + 255) / 256, 256, 0, stream>>>(W1, W1_b, DD * DD / 4);
  k_conv<<<(CC * DD / 4 + 255) / 256, 256, 0, stream>>>(W2, W2_b, CC * DD / 4);
  k_conv<<<(CC * DD / 4 + 255) / 256, 256, 0, stream>>>(cls, cls_b, CC * DD / 4);

  // history EMA -> vT
  k_count  <<<N_ROWS / 256, 256, 0, stream>>>(labels, cnt);
  k_scan   <<<1, CC, 0, stream>>>(cnt, offs);
  k_scatter<<<N_ROWS / 256, 256, 0, stream>>>(labels, offs, cursor, rowlist);
  k_v      <<<CC, 256, 0, stream>>>(x, hist, hcnt, cnt, offs, rowlist, vT);

  // gate
  k_g<<<N_ROWS / 4, 256, 0, stream>>>(x, W_g, b_g, g);

  // GEMM chain
  gemm_nt<0><<<dim3(CC / 128, N_ROWS / 128), 256, 0, stream>>>(R1, Wctx_b, DD, CC, b_ctx, nullptr, nullptr, R3, nullptr);
  gemm_nt<1><<<dim3(DD / 128, N_ROWS / 128), 256, 0, stream>>>(R2, W1_b,   DD, DD, b1,    nullptr, nullptr, R1, nullptr);
  gemm_nt<0><<<dim3(CC / 128, N_ROWS / 128), 256, 0, stream>>>(R1, W2_b,   DD, CC, b2,    nullptr, nullptr, R4, nullptr);

  k_stats<<<1024, 256, 0, stream>>>(R3, R4, labels, R3, accv);

  gemm_nt<2><<<dim3(DD / 128, N_ROWS / 128), 256, 0, stream>>>(R3, vT,    CC, DD, nullptr, g, x, R2, nullptr);
  gemm_nt<3><<<dim3(CC / 128, N_ROWS / 128), 256, 0, stream>>>(R2, cls_b, DD, CC, nullptr, nullptr, nullptr, nullptr, out + 1);

  // losses
  k_celog<<<1024, 256, 0, stream>>>(out + 1, labels, accv);
  k_final<<<1, 1, 0, stream>>>(accv, out);
}